// Round 3
// baseline (10.003 us; speedup 1.0000x reference)
//
#include <hip/hip_runtime.h>

typedef unsigned int uint32x4 __attribute__((ext_vector_type(4)));

__device__ __forceinline__ void full_add(uint32x4 a, uint32x4 b, uint32x4 c,
                                         uint32x4& s, uint32x4& co) {
    uint32x4 t = a ^ b;
    s  = t ^ c;
    co = (a & b) | (c & t);
}

// Per-bit majority (>=5 of 8) via carry-save adder tree on one vector slot.
__device__ __forceinline__ uint32x4 majority8(const uint32x4 x[8]) {
    uint32x4 s0, c0, s1, c1;
    full_add(x[0], x[1], x[2], s0, c0);
    full_add(x[3], x[4], x[5], s1, c1);
    uint32x4 s2 = x[6] ^ x[7];          // half adder
    uint32x4 c2 = x[6] & x[7];

    uint32x4 S, C, S2, C2;
    full_add(s0, s1, s2, S, C);         // S = ones, C = twos
    full_add(c0, c1, c2, S2, C2);       // S2 = twos, C2 = fours

    uint32x4 t = C ^ S2;                // twos bit
    uint32x4 u = C & S2;                // carry into fours
    uint32x4 f = C2 ^ u;                // fours bit
    uint32x4 e = C2 & u;                // eights bit

    // count >= 5  <=>  8 | (4 & (2|1))
    return e | (f & (t | S));
}

// Majority vote over V=8 voters, bit-sliced on 32-bit packed words.
// Each thread processes TWO uint32x4 slots: idx and idx+half (coalesced).
__global__ __launch_bounds__(256) void majority8_kernel(
        const uint32x4* __restrict__ src,   // V * M4 vectors (voter-major)
        uint32x4* __restrict__ out,         // M4 vectors
        int M4, int half) {
    int idx = blockIdx.x * blockDim.x + threadIdx.x;
    if (idx >= half) return;

    uint32x4 a[8], b[8];
#pragma unroll
    for (int v = 0; v < 8; ++v) {
        const uint32x4* p = src + (size_t)v * M4;
        a[v] = p[idx];
        b[v] = p[idx + half];
    }

    uint32x4 ra = majority8(a);
    uint32x4 rb = majority8(b);

    __builtin_nontemporal_store(ra, &out[idx]);
    __builtin_nontemporal_store(rb, &out[idx + half]);
}

extern "C" void kernel_launch(void* const* d_in, const int* in_sizes, int n_in,
                              void* d_out, int out_size, void* d_ws, size_t ws_size,
                              hipStream_t stream) {
    // d_in[0] = para_temp (float32, unused); d_in[1] = src (int32, V*M)
    const uint32x4* src = (const uint32x4*)d_in[1];
    uint32x4* out = (uint32x4*)d_out;

    int M    = out_size;      // 1048576 packed words
    int M4   = M / 4;         // 262144 vectors
    int half = M4 / 2;        // 131072 — each thread does 2 vectors

    int block = 256;
    int grid  = (half + block - 1) / block;   // 512 blocks
    majority8_kernel<<<grid, block, 0, stream>>>(src, out, M4, half);
}